// Round 2
// baseline (167.734 us; speedup 1.0000x reference)
//
#include <hip/hip_runtime.h>
#include <hip/hip_cooperative_groups.h>

namespace cg = cooperative_groups;

#define NT   2048          // number of distinct event times
#define NBLK 256           // grid blocks (== CU count, 1 block/CU)
#define TPB  1024
#define NW   (TPB / 64)    // waves per block

// ---------------------------------------------------------------------------
// Workspace layout
// ---------------------------------------------------------------------------
struct WsPtrs {
    float*    s_part;    // [NBLK][NT] fp32 per-block partial sums of e^hr
    float*    T_part;    // [NBLK][NT] fp32 per-block partial tied-event sums
    unsigned* n_part;    // [NBLK][NT] per-block tied-event counts
    double*   s_fin;     // [NT]
    double*   T_fin;     // [NT]
    double*   R;         // [NT] suffix sums (at-risk)
    unsigned* n_fin;     // [NT]
    double*   corr_part; // [NBLK]
    double*   hrE_part;  // [NBLK]
    double*   eCnt_part; // [NBLK]
};

__device__ __host__ __forceinline__ WsPtrs decode_ws(char* ws) {
    WsPtrs w;
    w.s_part = (float*)ws;
    w.T_part = (float*)(ws + (size_t)2 * 1024 * 1024);
    w.n_part = (unsigned*)(ws + (size_t)4 * 1024 * 1024);
    char* p  = ws + (size_t)6 * 1024 * 1024;
    w.s_fin  = (double*)p;    p += (size_t)NT * 8;
    w.T_fin  = (double*)p;    p += (size_t)NT * 8;
    w.R      = (double*)p;    p += (size_t)NT * 8;
    w.n_fin  = (unsigned*)p;  p += (size_t)NT * 4;
    w.corr_part = (double*)p; p += (size_t)NBLK * 8;
    w.hrE_part  = (double*)p; p += (size_t)NBLK * 8;
    w.eCnt_part = (double*)p;
    return w;
}

struct SharedMem {
    union {
        struct { float s[NT]; float T[NT]; unsigned n[NT]; } h;  // 24 KB
        struct { double a[NT]; double b[NT]; } sc;               // 32 KB
    } u;
    double redA[NW], redB[NW], redC[NW];
    double corr_g[8];
};

__device__ __forceinline__ double wave_reduce(double v) {
#pragma unroll
    for (int o = 32; o > 0; o >>= 1) v += __shfl_down(v, o, 64);
    return v;
}

// ---------------------------------------------------------------------------
// Phase 0: per-block LDS histogram (vectorized int4/float4 loads)
// ---------------------------------------------------------------------------
__device__ void phase_hist(const float* __restrict__ hr, const int* __restrict__ dur,
                           const int* __restrict__ ev, int n, const WsPtrs& w,
                           SharedMem& sm, int bid, int tid)
{
    for (int i = tid; i < NT; i += TPB) {
        sm.u.h.s[i] = 0.f; sm.u.h.T[i] = 0.f; sm.u.h.n[i] = 0u;
    }
    __syncthreads();

    double hrE = 0.0, ec = 0.0;
    const float4* hr4 = (const float4*)hr;
    const int4*   d4p = (const int4*)dur;
    const int4*   e4p = (const int4*)ev;
    const int nv = n >> 2;
    const int stride = NBLK * TPB;

#pragma unroll 4
    for (int i = bid * TPB + tid; i < nv; i += stride) {
        float4 h = hr4[i];
        int4   d = d4p[i];
        int4   e = e4p[i];
        float eh0 = expf(h.x), eh1 = expf(h.y), eh2 = expf(h.z), eh3 = expf(h.w);
        atomicAdd(&sm.u.h.s[d.x], eh0);
        atomicAdd(&sm.u.h.s[d.y], eh1);
        atomicAdd(&sm.u.h.s[d.z], eh2);
        atomicAdd(&sm.u.h.s[d.w], eh3);
        if (e.x) { atomicAdd(&sm.u.h.T[d.x], eh0); atomicAdd(&sm.u.h.n[d.x], 1u); hrE += (double)h.x; ec += 1.0; }
        if (e.y) { atomicAdd(&sm.u.h.T[d.y], eh1); atomicAdd(&sm.u.h.n[d.y], 1u); hrE += (double)h.y; ec += 1.0; }
        if (e.z) { atomicAdd(&sm.u.h.T[d.z], eh2); atomicAdd(&sm.u.h.n[d.z], 1u); hrE += (double)h.z; ec += 1.0; }
        if (e.w) { atomicAdd(&sm.u.h.T[d.w], eh3); atomicAdd(&sm.u.h.n[d.w], 1u); hrE += (double)h.w; ec += 1.0; }
    }
    // scalar tail (n not divisible by 4)
    for (int i = (nv << 2) + bid * TPB + tid; i < n; i += stride) {
        float h = hr[i]; int d = dur[i]; int e = ev[i];
        float eh = expf(h);
        atomicAdd(&sm.u.h.s[d], eh);
        if (e) { atomicAdd(&sm.u.h.T[d], eh); atomicAdd(&sm.u.h.n[d], 1u); hrE += (double)h; ec += 1.0; }
    }
    __syncthreads();

    size_t base = (size_t)bid * NT;
    for (int i = tid; i < NT; i += TPB) {
        w.s_part[base + i] = sm.u.h.s[i];
        w.T_part[base + i] = sm.u.h.T[i];
        w.n_part[base + i] = sm.u.h.n[i];
    }

    hrE = wave_reduce(hrE);
    ec  = wave_reduce(ec);
    if ((tid & 63) == 0) { sm.redA[tid >> 6] = hrE; sm.redB[tid >> 6] = ec; }
    __syncthreads();
    if (tid == 0) {
        double hh = 0.0, cc = 0.0;
#pragma unroll
        for (int i = 0; i < NW; ++i) { hh += sm.redA[i]; cc += sm.redB[i]; }
        w.hrE_part[bid]  = hh;
        w.eCnt_part[bid] = cc;
    }
}

// ---------------------------------------------------------------------------
// Phase 1: reduce partials across blocks. Block b owns bins [b*8, b*8+8);
// group g (128 threads) reduces one bin over NBLK partials.
// ---------------------------------------------------------------------------
__device__ void phase_reduce(const WsPtrs& w, SharedMem& sm, int bid, int tid)
{
    int g = tid >> 7;          // group 0..7
    int l = tid & 127;         // lane-in-group
    int t = bid * 8 + g;       // bin
    double s = 0.0, T = 0.0, c = 0.0;
    for (int j = l; j < NBLK; j += 128) {
        size_t idx = (size_t)j * NT + t;
        s += (double)w.s_part[idx];
        T += (double)w.T_part[idx];
        c += (double)w.n_part[idx];
    }
    s = wave_reduce(s); T = wave_reduce(T); c = wave_reduce(c);
    int wv = tid >> 6;
    if ((tid & 63) == 0) { sm.redA[wv] = s; sm.redB[wv] = T; sm.redC[wv] = c; }
    __syncthreads();
    if (l == 0) {
        double ss = sm.redA[2 * g] + sm.redA[2 * g + 1];
        double TT = sm.redB[2 * g] + sm.redB[2 * g + 1];
        double cc = sm.redC[2 * g] + sm.redC[2 * g + 1];
        w.s_fin[t] = ss;
        w.T_fin[t] = TT;
        w.n_fin[t] = (unsigned)(cc + 0.5);
    }
}

// ---------------------------------------------------------------------------
// Phase 2: suffix cumsum R[t] = sum_{t'>=t} s[t']  (block 0 only, LDS scan)
// ---------------------------------------------------------------------------
__device__ void phase_scan(const WsPtrs& w, SharedMem& sm, int bid, int tid)
{
    if (bid != 0) return;
    for (int i = tid; i < NT; i += TPB) sm.u.sc.a[i] = w.s_fin[i];
    __syncthreads();
    double* cur = sm.u.sc.a;
    double* nxt = sm.u.sc.b;
    for (int off = 1; off < NT; off <<= 1) {
        for (int i = tid; i < NT; i += TPB) {
            double v = cur[i];
            if (i + off < NT) v += cur[i + off];
            nxt[i] = v;
        }
        __syncthreads();
        double* tmp = cur; cur = nxt; nxt = tmp;
    }
    for (int i = tid; i < NT; i += TPB) w.R[i] = cur[i];
}

// ---------------------------------------------------------------------------
// Phase 3: Efron correction: corr[t] = sum_{k=0}^{n_t-1} log(R[t]-(k/n_t)T[t])
// Same bin<->group mapping as phase 1.
// ---------------------------------------------------------------------------
__device__ void phase_efron(const WsPtrs& w, SharedMem& sm, int bid, int tid)
{
    int g = tid >> 7;
    int l = tid & 127;
    int t = bid * 8 + g;
    unsigned nt = w.n_fin[t];
    double acc = 0.0;
    if (nt > 0) {
        double Rt = w.R[t];
        double Tt = w.T_fin[t];
        double inv = 1.0 / (double)nt;
        for (unsigned k = l; k < nt; k += 128) {
            float arg = (float)(Rt - ((double)k * inv) * Tt);
            acc += (double)logf(arg);
        }
    }
    acc = wave_reduce(acc);
    if ((tid & 63) == 0) sm.redA[tid >> 6] = acc;
    __syncthreads();
    if (l == 0) sm.corr_g[g] = sm.redA[2 * g] + sm.redA[2 * g + 1];
    __syncthreads();
    if (tid == 0) {
        double c = 0.0;
#pragma unroll
        for (int i = 0; i < 8; ++i) c += sm.corr_g[i];
        w.corr_part[bid] = c;
    }
}

// ---------------------------------------------------------------------------
// Phase 4: final reduction and loss (block 0 only)
// ---------------------------------------------------------------------------
__device__ void phase_final(const WsPtrs& w, SharedMem& sm, int bid, int tid,
                            float* __restrict__ out)
{
    if (bid != 0) return;
    double a = 0.0, h = 0.0, c = 0.0;
    if (tid < NBLK) {
        a = w.corr_part[tid];
        h = w.hrE_part[tid];
        c = w.eCnt_part[tid];
    }
    a = wave_reduce(a); h = wave_reduce(h); c = wave_reduce(c);
    if ((tid & 63) == 0) { sm.redA[tid >> 6] = a; sm.redB[tid >> 6] = h; sm.redC[tid >> 6] = c; }
    __syncthreads();
    if (tid == 0) {
        double corr = 0.0, hh = 0.0, cc = 0.0;
#pragma unroll
        for (int i = 0; i < 4; ++i) { corr += sm.redA[i]; hh += sm.redB[i]; cc += sm.redC[i]; }
        double loss = hh - corr;
        out[0] = (float)(-loss / (cc + 1e-7));
    }
}

// ---------------------------------------------------------------------------
// Single cooperative kernel: all phases with grid-wide syncs
// ---------------------------------------------------------------------------
extern "C" __global__ void __launch_bounds__(TPB)
cox_mono(const float* __restrict__ hr, const int* __restrict__ dur,
         const int* __restrict__ ev, int n, char* ws, float* out)
{
    __shared__ SharedMem sm;
    WsPtrs w = decode_ws(ws);
    cg::grid_group grid = cg::this_grid();
    int bid = blockIdx.x, tid = threadIdx.x;

    phase_hist(hr, dur, ev, n, w, sm, bid, tid);
    grid.sync();
    phase_reduce(w, sm, bid, tid);
    grid.sync();
    phase_scan(w, sm, bid, tid);
    grid.sync();
    phase_efron(w, sm, bid, tid);
    grid.sync();
    phase_final(w, sm, bid, tid, out);
}

// ---------------------------------------------------------------------------
// Fallback: same phases as separate kernels (if cooperative launch fails)
// ---------------------------------------------------------------------------
__global__ void __launch_bounds__(TPB) k_hist(const float* __restrict__ hr,
    const int* __restrict__ dur, const int* __restrict__ ev, int n, char* ws)
{
    __shared__ SharedMem sm;
    WsPtrs w = decode_ws(ws);
    phase_hist(hr, dur, ev, n, w, sm, blockIdx.x, threadIdx.x);
}
__global__ void __launch_bounds__(TPB) k_reduce(char* ws)
{
    __shared__ SharedMem sm;
    WsPtrs w = decode_ws(ws);
    phase_reduce(w, sm, blockIdx.x, threadIdx.x);
}
__global__ void __launch_bounds__(TPB) k_scan(char* ws)
{
    __shared__ SharedMem sm;
    WsPtrs w = decode_ws(ws);
    phase_scan(w, sm, blockIdx.x, threadIdx.x);
}
__global__ void __launch_bounds__(TPB) k_efron(char* ws)
{
    __shared__ SharedMem sm;
    WsPtrs w = decode_ws(ws);
    phase_efron(w, sm, blockIdx.x, threadIdx.x);
}
__global__ void __launch_bounds__(TPB) k_final(char* ws, float* out)
{
    __shared__ SharedMem sm;
    WsPtrs w = decode_ws(ws);
    phase_final(w, sm, blockIdx.x, threadIdx.x, out);
}

// ---------------------------------------------------------------------------
extern "C" void kernel_launch(void* const* d_in, const int* in_sizes, int n_in,
                              void* d_out, int out_size, void* d_ws, size_t ws_size,
                              hipStream_t stream)
{
    const float* hr  = (const float*)d_in[0];
    const int*   dur = (const int*)d_in[1];
    const int*   ev  = (const int*)d_in[2];
    int n = in_sizes[1];
    char* ws = (char*)d_ws;
    float* out = (float*)d_out;

    void* args[] = { (void*)&hr, (void*)&dur, (void*)&ev, (void*)&n, (void*)&ws, (void*)&out };
    hipError_t err = hipLaunchCooperativeKernel((void*)cox_mono, dim3(NBLK), dim3(TPB),
                                                args, 0, stream);
    if (err != hipSuccess) {
        // deterministic fallback: same phases as a 5-kernel pipeline
        hipLaunchKernelGGL(k_hist,   dim3(NBLK), dim3(TPB), 0, stream, hr, dur, ev, n, ws);
        hipLaunchKernelGGL(k_reduce, dim3(NBLK), dim3(TPB), 0, stream, ws);
        hipLaunchKernelGGL(k_scan,   dim3(1),    dim3(TPB), 0, stream, ws);
        hipLaunchKernelGGL(k_efron,  dim3(NBLK), dim3(TPB), 0, stream, ws);
        hipLaunchKernelGGL(k_final,  dim3(1),    dim3(TPB), 0, stream, ws, out);
    }
}

// Round 3
// 66.480 us; speedup vs baseline: 2.5231x; 2.5231x over previous
//
#include <hip/hip_runtime.h>

#define NT 2048          // number of distinct event times
#define HB 256           // hist blocks
#define HT 1024          // hist threads per block
#define RB 32            // reduce blocks  (64 bins each)
#define RT 1024
#define EB 32            // efron blocks   (64 bins each)
#define ET 1024

__device__ __forceinline__ double wave_reduce(double v) {
#pragma unroll
    for (int o = 32; o > 0; o >>= 1) v += __shfl_down(v, o, 64);
    return v;
}

// ---------------------------------------------------------------------------
// K1: per-block LDS histogram. Fully staged float4/int4 loads (12 loads in
// flight per thread) -> fp32 per-block partials. Also per-block sum(hr*e),
// sum(e) in fp64, and zeroes the K3 ticket counter.
// ---------------------------------------------------------------------------
__global__ __launch_bounds__(HT) void k_hist(
    const float* __restrict__ hr, const int* __restrict__ dur,
    const int* __restrict__ ev, int n,
    float* __restrict__ s_part, float* __restrict__ T_part,
    unsigned* __restrict__ n_part,
    double* __restrict__ hrE_part, double* __restrict__ eCnt_part,
    unsigned* __restrict__ counter)
{
    __shared__ float    s_loc[NT];
    __shared__ float    T_loc[NT];
    __shared__ unsigned n_loc[NT];
    __shared__ double   redH[HT / 64], redC[HT / 64];

    const int tid = threadIdx.x, bid = blockIdx.x;
    if (bid == 0 && tid == 0) *counter = 0u;   // ticket for K3's last-block

    for (int i = tid; i < NT; i += HT) { s_loc[i] = 0.f; T_loc[i] = 0.f; n_loc[i] = 0u; }
    __syncthreads();

    double hrE = 0.0, ec = 0.0;
    const int stride = HB * HT;
    const int nv = n >> 2;
    const float4* hr4 = (const float4*)hr;
    const int4*   d4p = (const int4*)dur;
    const int4*   e4p = (const int4*)ev;

    auto process = [&](float4 h, int4 d, int4 e) {
        float eh0 = expf(h.x), eh1 = expf(h.y), eh2 = expf(h.z), eh3 = expf(h.w);
        atomicAdd(&s_loc[d.x], eh0);
        atomicAdd(&s_loc[d.y], eh1);
        atomicAdd(&s_loc[d.z], eh2);
        atomicAdd(&s_loc[d.w], eh3);
        if (e.x) { atomicAdd(&T_loc[d.x], eh0); atomicAdd(&n_loc[d.x], 1u); hrE += (double)h.x; ec += 1.0; }
        if (e.y) { atomicAdd(&T_loc[d.y], eh1); atomicAdd(&n_loc[d.y], 1u); hrE += (double)h.y; ec += 1.0; }
        if (e.z) { atomicAdd(&T_loc[d.z], eh2); atomicAdd(&n_loc[d.z], 1u); hrE += (double)h.z; ec += 1.0; }
        if (e.w) { atomicAdd(&T_loc[d.w], eh3); atomicAdd(&n_loc[d.w], 1u); hrE += (double)h.w; ec += 1.0; }
    };

    int i = bid * HT + tid;
    if (i + 3 * stride < nv) {                // N = 2^22: every thread lands here
        float4 h[4]; int4 d[4], e[4];
#pragma unroll
        for (int u = 0; u < 4; ++u) {         // 12 independent 16B loads, max MLP
            h[u] = hr4[i + u * stride];
            d[u] = d4p[i + u * stride];
            e[u] = e4p[i + u * stride];
        }
#pragma unroll
        for (int u = 0; u < 4; ++u) process(h[u], d[u], e[u]);
        i += 4 * stride;
    }
    for (; i < nv; i += stride) process(hr4[i], d4p[i], e4p[i]);   // generic rest
    for (int j = (nv << 2) + bid * HT + tid; j < n; j += stride) { // scalar tail
        float h = hr[j]; int d = dur[j]; int e = ev[j];
        float eh = expf(h);
        atomicAdd(&s_loc[d], eh);
        if (e) { atomicAdd(&T_loc[d], eh); atomicAdd(&n_loc[d], 1u); hrE += (double)h; ec += 1.0; }
    }
    __syncthreads();

    size_t base = (size_t)bid * NT;
    for (int k = tid; k < NT; k += HT) {
        s_part[base + k] = s_loc[k];
        T_part[base + k] = T_loc[k];
        n_part[base + k] = n_loc[k];
    }

    hrE = wave_reduce(hrE);
    ec  = wave_reduce(ec);
    if ((tid & 63) == 0) { redH[tid >> 6] = hrE; redC[tid >> 6] = ec; }
    __syncthreads();
    if (tid == 0) {
        double hh = 0.0, cc = 0.0;
#pragma unroll
        for (int w = 0; w < HT / 64; ++w) { hh += redH[w]; cc += redC[w]; }
        hrE_part[bid]  = hh;
        eCnt_part[bid] = cc;
    }
}

// ---------------------------------------------------------------------------
// K2: reduce per-block partials -> s_fin/T_fin/n_fin. 32 blocks x 1024.
// Block owns 64 bins; 16 j-groups of 64 lanes each read coalesced 256B runs.
// ---------------------------------------------------------------------------
__global__ __launch_bounds__(RT) void k_reduce(
    const float* __restrict__ s_part, const float* __restrict__ T_part,
    const unsigned* __restrict__ n_part,
    double* __restrict__ s_fin, double* __restrict__ T_fin,
    unsigned* __restrict__ n_fin)
{
    __shared__ double   rs[16][64];
    __shared__ double   rt[16][64];
    __shared__ unsigned rn[16][64];

    const int bi = threadIdx.x & 63;
    const int jg = threadIdx.x >> 6;
    const int t  = blockIdx.x * 64 + bi;

    double s = 0.0, T = 0.0;
    unsigned c = 0u;
#pragma unroll 4
    for (int m = 0; m < 16; ++m) {
        int j = jg + (m << 4);
        size_t idx = (size_t)j * NT + t;
        s += (double)s_part[idx];
        T += (double)T_part[idx];
        c += n_part[idx];
    }
    rs[jg][bi] = s; rt[jg][bi] = T; rn[jg][bi] = c;
    __syncthreads();
    if (jg == 0) {
        double S = 0.0, TT = 0.0; unsigned C = 0u;
#pragma unroll
        for (int m = 0; m < 16; ++m) { S += rs[m][bi]; TT += rt[m][bi]; C += rn[m][bi]; }
        s_fin[t] = S;
        T_fin[t] = TT;
        n_fin[t] = C;
    }
}

// ---------------------------------------------------------------------------
// K3: each block redundantly suffix-scans s_fin (2048 doubles) in LDS, does
// the Efron correction for its 64 bins, then the LAST block (ticket atomic,
// no spin) reduces everything and writes the loss.
// ---------------------------------------------------------------------------
__global__ __launch_bounds__(ET) void k_scan_efron_final(
    const double* __restrict__ s_fin, const double* __restrict__ T_fin,
    const unsigned* __restrict__ n_fin,
    double* __restrict__ corr_part, const double* __restrict__ hrE_part,
    const double* __restrict__ eCnt_part,
    unsigned* __restrict__ counter, float* __restrict__ out)
{
    __shared__ double sa[NT];
    __shared__ double sb[NT];
    __shared__ double red[16][64];
    __shared__ unsigned is_last;

    const int tid = threadIdx.x, bid = blockIdx.x;

    // --- suffix scan (Hillis-Steele, ping-pong) ---
    for (int i = tid; i < NT; i += ET) sa[i] = s_fin[i];
    __syncthreads();
    double* cur = sa;
    double* nxt = sb;
    for (int off = 1; off < NT; off <<= 1) {
        for (int i = tid; i < NT; i += ET) {
            double v = cur[i];
            if (i + off < NT) v += cur[i + off];
            nxt[i] = v;
        }
        __syncthreads();
        double* tmp = cur; cur = nxt; nxt = tmp;
    }

    // --- Efron correction for this block's 64 bins (16 lanes per bin) ---
    const int bi = tid & 63;
    const int kl = tid >> 6;
    const int t  = bid * 64 + bi;
    unsigned nt = n_fin[t];
    double acc = 0.0;
    if (nt > 0) {
        double Rt = cur[t];
        double Tt = T_fin[t];
        double inv = 1.0 / (double)nt;
        for (unsigned k = kl; k < nt; k += 16)
            acc += (double)logf((float)(Rt - (double)k * inv * Tt));
    }
    red[kl][bi] = acc;
    __syncthreads();
    if (kl == 0) {
        double c = 0.0;
#pragma unroll
        for (int m = 0; m < 16; ++m) c += red[m][bi];
#pragma unroll
        for (int o = 32; o > 0; o >>= 1) c += __shfl_down(c, o, 64);
        if (bi == 0) corr_part[bid] = c;
    }
    __syncthreads();

    // --- last-block final reduction ---
    if (tid == 0) {
        __threadfence();                           // release corr_part[bid]
        unsigned ticket = atomicAdd(counter, 1u);
        is_last = (ticket == EB - 1) ? 1u : 0u;
    }
    __syncthreads();
    if (is_last) {
        __threadfence();                           // acquire other blocks' writes
        double a = 0.0, h = 0.0, c = 0.0;
        if (tid < EB) a = corr_part[tid];
        if (tid < HB) { h = hrE_part[tid]; c = eCnt_part[tid]; }
        a = wave_reduce(a); h = wave_reduce(h); c = wave_reduce(c);
        if ((tid & 63) == 0) { red[0][tid >> 6] = a; red[1][tid >> 6] = h; red[2][tid >> 6] = c; }
        __syncthreads();
        if (tid == 0) {
            double A = 0.0, H = 0.0, C = 0.0;
#pragma unroll
            for (int w = 0; w < 16; ++w) { A += red[0][w]; H += red[1][w]; C += red[2][w]; }
            out[0] = (float)(-(H - A) / (C + 1e-7));
        }
    }
}

// ---------------------------------------------------------------------------
extern "C" void kernel_launch(void* const* d_in, const int* in_sizes, int n_in,
                              void* d_out, int out_size, void* d_ws, size_t ws_size,
                              hipStream_t stream)
{
    const float* hr  = (const float*)d_in[0];
    const int*   dur = (const int*)d_in[1];
    const int*   ev  = (const int*)d_in[2];
    int n = in_sizes[1];

    char* ws = (char*)d_ws;
    float*    s_part    = (float*)ws;                               // 2 MB
    float*    T_part    = (float*)(ws + (size_t)2 * 1024 * 1024);   // 2 MB
    unsigned* n_part    = (unsigned*)(ws + (size_t)4 * 1024 * 1024);// 2 MB
    char*     p         = ws + (size_t)6 * 1024 * 1024;
    double*   s_fin     = (double*)p;          p += NT * 8;
    double*   T_fin     = (double*)p;          p += NT * 8;
    unsigned* n_fin     = (unsigned*)p;        p += NT * 4;
    double*   corr_part = (double*)p;          p += EB * 8;
    double*   hrE_part  = (double*)p;          p += HB * 8;
    double*   eCnt_part = (double*)p;          p += HB * 8;
    unsigned* counter   = (unsigned*)p;

    hipLaunchKernelGGL(k_hist, dim3(HB), dim3(HT), 0, stream,
                       hr, dur, ev, n, s_part, T_part, n_part,
                       hrE_part, eCnt_part, counter);
    hipLaunchKernelGGL(k_reduce, dim3(RB), dim3(RT), 0, stream,
                       s_part, T_part, n_part, s_fin, T_fin, n_fin);
    hipLaunchKernelGGL(k_scan_efron_final, dim3(EB), dim3(ET), 0, stream,
                       s_fin, T_fin, n_fin, corr_part, hrE_part, eCnt_part,
                       counter, (float*)d_out);
}

// Round 4
// 48.525 us; speedup vs baseline: 3.4566x; 1.3700x over previous
//
#include <hip/hip_runtime.h>

#define NT 2048            // number of distinct event times
#define HB 512             // hist blocks (2 per CU -> 100% occupancy)
#define HT 1024            // hist threads per block
#define RB 32              // reduce blocks (64 bins each)
#define RT 1024
#define EB 32              // efron blocks (64 bins each)
#define ET 1024

#define FXSCALE    2147483648.0      // 2^31 fixed-point scale
#define INV_FXSCALE (1.0 / 2147483648.0)
#define TMASK ((1ULL << 56) - 1)     // low 56 bits: T sum; high 8: event count

typedef unsigned long long u64;

__device__ __forceinline__ double wave_reduce(double v) {
#pragma unroll
    for (int o = 32; o > 0; o >>= 1) v += __shfl_down(v, o, 64);
    return v;
}

// ---------------------------------------------------------------------------
// K1: per-block LDS histogram with NATIVE u64 integer atomics (ds_add_u64).
//   s_loc[bin]  += fx(e^hr)                    (u64, scale 2^31)
//   tn_loc[bin] += fx(e^hr) | (1<<56)  if event (T in low 56, count in top 8)
// Also per-block fp64 sum(hr*e), sum(e); zeroes K3's ticket counter.
// ---------------------------------------------------------------------------
__global__ __launch_bounds__(HT) void k_hist(
    const float* __restrict__ hr, const int* __restrict__ dur,
    const int* __restrict__ ev, int n,
    u64* __restrict__ s_part, u64* __restrict__ tn_part,
    double* __restrict__ hrE_part, double* __restrict__ eCnt_part,
    unsigned* __restrict__ counter)
{
    __shared__ u64    s_loc[NT];    // 16 KB
    __shared__ u64    tn_loc[NT];   // 16 KB
    __shared__ double redH[HT / 64], redC[HT / 64];

    const int tid = threadIdx.x, bid = blockIdx.x;
    if (bid == 0 && tid == 0) *counter = 0u;

    for (int i = tid; i < NT; i += HT) { s_loc[i] = 0ull; tn_loc[i] = 0ull; }
    __syncthreads();

    double hrE = 0.0, ec = 0.0;
    const int stride = HB * HT;
    const int nv = n >> 2;
    const float4* hr4 = (const float4*)hr;
    const int4*   d4p = (const int4*)dur;
    const int4*   e4p = (const int4*)ev;

    auto process = [&](const float4& h, const int4& d, const int4& e) {
        float hh[4] = { h.x, h.y, h.z, h.w };
        int   dd[4] = { d.x, d.y, d.z, d.w };
        int   ee[4] = { e.x, e.y, e.z, e.w };
#pragma unroll
        for (int u = 0; u < 4; ++u) {
            float eh = expf(hh[u]);
            u64 fx = (u64)((double)eh * FXSCALE + 0.5);
            atomicAdd(&s_loc[dd[u]], fx);
            if (ee[u]) {
                atomicAdd(&tn_loc[dd[u]], fx | (1ULL << 56));
                hrE += (double)hh[u];
                ec  += 1.0;
            }
        }
    };

    // N = 2^22: nv = 1M vec4 groups over 512K threads -> exactly 2 iterations,
    // staged as one pair (6 independent 16B loads in flight).
    for (int i = bid * HT + tid; i < nv; i += 2 * stride) {
        const bool two = (i + stride) < nv;
        float4 h0 = hr4[i];
        int4   d0 = d4p[i];
        int4   e0 = e4p[i];
        float4 h1; int4 d1, e1;
        if (two) { h1 = hr4[i + stride]; d1 = d4p[i + stride]; e1 = e4p[i + stride]; }
        process(h0, d0, e0);
        if (two) process(h1, d1, e1);
    }
    // scalar tail (n not divisible by 4)
    for (int j = (nv << 2) + bid * HT + tid; j < n; j += stride) {
        float h = hr[j]; int d = dur[j]; int e = ev[j];
        float eh = expf(h);
        u64 fx = (u64)((double)eh * FXSCALE + 0.5);
        atomicAdd(&s_loc[d], fx);
        if (e) { atomicAdd(&tn_loc[d], fx | (1ULL << 56)); hrE += (double)h; ec += 1.0; }
    }
    __syncthreads();

    const size_t base = (size_t)bid * NT;
    for (int k = tid; k < NT; k += HT) {
        s_part[base + k]  = s_loc[k];
        tn_part[base + k] = tn_loc[k];
    }

    hrE = wave_reduce(hrE);
    ec  = wave_reduce(ec);
    if ((tid & 63) == 0) { redH[tid >> 6] = hrE; redC[tid >> 6] = ec; }
    __syncthreads();
    if (tid == 0) {
        double hh = 0.0, cc = 0.0;
#pragma unroll
        for (int w = 0; w < HT / 64; ++w) { hh += redH[w]; cc += redC[w]; }
        hrE_part[bid]  = hh;
        eCnt_part[bid] = cc;
    }
}

// ---------------------------------------------------------------------------
// K2: exact u64 reduction of partials -> s_fin/T_fin (double), n_fin (u32).
// Block owns 64 bins; 16 j-groups x 32 partial-rows each, coalesced.
// ---------------------------------------------------------------------------
__global__ __launch_bounds__(RT) void k_reduce(
    const u64* __restrict__ s_part, const u64* __restrict__ tn_part,
    double* __restrict__ s_fin, double* __restrict__ T_fin,
    unsigned* __restrict__ n_fin)
{
    __shared__ u64      rs[16][64];
    __shared__ u64      rt[16][64];
    __shared__ unsigned rn[16][64];

    const int bi = threadIdx.x & 63;
    const int jg = threadIdx.x >> 6;
    const int t  = blockIdx.x * 64 + bi;

    u64 s = 0ull, T = 0ull;
    unsigned c = 0u;
#pragma unroll 4
    for (int m = 0; m < HB / 16; ++m) {
        int j = jg + (m << 4);
        size_t idx = (size_t)j * NT + t;
        s += s_part[idx];
        u64 v = tn_part[idx];
        T += v & TMASK;
        c += (unsigned)(v >> 56);
    }
    rs[jg][bi] = s; rt[jg][bi] = T; rn[jg][bi] = c;
    __syncthreads();
    if (jg == 0) {
        u64 S = 0ull, TT = 0ull; unsigned C = 0u;
#pragma unroll
        for (int m = 0; m < 16; ++m) { S += rs[m][bi]; TT += rt[m][bi]; C += rn[m][bi]; }
        s_fin[t] = (double)S * INV_FXSCALE;
        T_fin[t] = (double)TT * INV_FXSCALE;
        n_fin[t] = C;
    }
}

// ---------------------------------------------------------------------------
// K3: each block redundantly suffix-scans s_fin (2048 doubles) in LDS, does
// the Efron correction for its 64 bins, then the LAST block (ticket atomic,
// no spin) reduces everything and writes the loss.
// ---------------------------------------------------------------------------
__global__ __launch_bounds__(ET) void k_scan_efron_final(
    const double* __restrict__ s_fin, const double* __restrict__ T_fin,
    const unsigned* __restrict__ n_fin,
    double* __restrict__ corr_part, const double* __restrict__ hrE_part,
    const double* __restrict__ eCnt_part,
    unsigned* __restrict__ counter, float* __restrict__ out)
{
    __shared__ double sa[NT];
    __shared__ double sb[NT];
    __shared__ double red[16][64];
    __shared__ unsigned is_last;

    const int tid = threadIdx.x, bid = blockIdx.x;

    // --- suffix scan (Hillis-Steele, ping-pong) ---
    for (int i = tid; i < NT; i += ET) sa[i] = s_fin[i];
    __syncthreads();
    double* cur = sa;
    double* nxt = sb;
    for (int off = 1; off < NT; off <<= 1) {
        for (int i = tid; i < NT; i += ET) {
            double v = cur[i];
            if (i + off < NT) v += cur[i + off];
            nxt[i] = v;
        }
        __syncthreads();
        double* tmp = cur; cur = nxt; nxt = tmp;
    }

    // --- Efron correction for this block's 64 bins (16 lanes per bin) ---
    const int bi = tid & 63;
    const int kl = tid >> 6;
    const int t  = bid * 64 + bi;
    unsigned nt = n_fin[t];
    double acc = 0.0;
    if (nt > 0) {
        double Rt = cur[t];
        double Tt = T_fin[t];
        double inv = 1.0 / (double)nt;
        for (unsigned k = kl; k < nt; k += 16)
            acc += (double)logf((float)(Rt - (double)k * inv * Tt));
    }
    red[kl][bi] = acc;
    __syncthreads();
    if (kl == 0) {
        double c = 0.0;
#pragma unroll
        for (int m = 0; m < 16; ++m) c += red[m][bi];
#pragma unroll
        for (int o = 32; o > 0; o >>= 1) c += __shfl_down(c, o, 64);
        if (bi == 0) corr_part[bid] = c;
    }
    __syncthreads();

    // --- last-block final reduction ---
    if (tid == 0) {
        __threadfence();
        unsigned ticket = atomicAdd(counter, 1u);
        is_last = (ticket == EB - 1) ? 1u : 0u;
    }
    __syncthreads();
    if (is_last) {
        __threadfence();
        double a = 0.0, h = 0.0, c = 0.0;
        if (tid < EB) a = corr_part[tid];
        if (tid < HB) { h = hrE_part[tid]; c = eCnt_part[tid]; }
        a = wave_reduce(a); h = wave_reduce(h); c = wave_reduce(c);
        if ((tid & 63) == 0) { red[0][tid >> 6] = a; red[1][tid >> 6] = h; red[2][tid >> 6] = c; }
        __syncthreads();
        if (tid == 0) {
            double A = 0.0, H = 0.0, C = 0.0;
#pragma unroll
            for (int w = 0; w < 16; ++w) { A += red[0][w]; H += red[1][w]; C += red[2][w]; }
            out[0] = (float)(-(H - A) / (C + 1e-7));
        }
    }
}

// ---------------------------------------------------------------------------
extern "C" void kernel_launch(void* const* d_in, const int* in_sizes, int n_in,
                              void* d_out, int out_size, void* d_ws, size_t ws_size,
                              hipStream_t stream)
{
    const float* hr  = (const float*)d_in[0];
    const int*   dur = (const int*)d_in[1];
    const int*   ev  = (const int*)d_in[2];
    int n = in_sizes[1];

    char* ws = (char*)d_ws;
    u64*      s_part    = (u64*)ws;                                  // 512*2048*8 = 8 MB
    u64*      tn_part   = (u64*)(ws + (size_t)8 * 1024 * 1024);      // 8 MB
    char*     p         = ws + (size_t)16 * 1024 * 1024;
    double*   s_fin     = (double*)p;          p += NT * 8;
    double*   T_fin     = (double*)p;          p += NT * 8;
    unsigned* n_fin     = (unsigned*)p;        p += NT * 4;
    double*   corr_part = (double*)p;          p += EB * 8;
    double*   hrE_part  = (double*)p;          p += HB * 8;
    double*   eCnt_part = (double*)p;          p += HB * 8;
    unsigned* counter   = (unsigned*)p;

    hipLaunchKernelGGL(k_hist, dim3(HB), dim3(HT), 0, stream,
                       hr, dur, ev, n, s_part, tn_part, hrE_part, eCnt_part, counter);
    hipLaunchKernelGGL(k_reduce, dim3(RB), dim3(RT), 0, stream,
                       s_part, tn_part, s_fin, T_fin, n_fin);
    hipLaunchKernelGGL(k_scan_efron_final, dim3(EB), dim3(ET), 0, stream,
                       s_fin, T_fin, n_fin, corr_part, hrE_part, eCnt_part,
                       counter, (float*)d_out);
}

// Round 5
// 43.218 us; speedup vs baseline: 3.8811x; 1.1228x over previous
//
#include <hip/hip_runtime.h>

#define NT 2048            // number of distinct event times
#define HB 512             // hist blocks (2 per CU)
#define HT 1024            // hist threads per block
#define RB 32              // reduce blocks (64 bins each)
#define RT 1024
#define EB 128             // efron blocks (16 bins each, 1 wave per bin)
#define ET 1024

#define FXSCALE     2147483648.0     // 2^31 fixed-point scale
#define INV_FXSCALE (1.0 / 2147483648.0)
#define TMASK ((1ULL << 56) - 1)     // low 56 bits: scaled sum; high 8: count

typedef unsigned long long u64;

__device__ __forceinline__ double wave_reduce(double v) {
#pragma unroll
    for (int o = 32; o > 0; o >>= 1) v += __shfl_down(v, o, 64);
    return v;
}

// ---------------------------------------------------------------------------
// K1: per-block LDS histogram, EXACTLY ONE u64 atomic per sample, branchless.
//   loc[d + e*NT] += fx(e^hr) | ((u64)e << 56)
// Censored samples accumulate in loc[0..NT) ("s0"); event samples in
// loc[NT..2NT) ("tn": T in low 56 bits, event count in top 8 bits).
// s[t] = s0[t] + (tn[t] & TMASK). Also per-block fp64 sum(hr*e), sum(e).
// ---------------------------------------------------------------------------
__global__ __launch_bounds__(HT) void k_hist(
    const float* __restrict__ hr, const int* __restrict__ dur,
    const int* __restrict__ ev, int n,
    u64* __restrict__ s0_part, u64* __restrict__ tn_part,
    double* __restrict__ hrE_part, double* __restrict__ eCnt_part,
    unsigned* __restrict__ counter)
{
    __shared__ u64    loc[2 * NT];   // 32 KB
    __shared__ double redH[HT / 64], redC[HT / 64];

    const int tid = threadIdx.x, bid = blockIdx.x;
    if (bid == 0 && tid == 0) *counter = 0u;

    for (int i = tid; i < 2 * NT; i += HT) loc[i] = 0ull;
    __syncthreads();

    double hrE = 0.0, ec = 0.0;
    const int stride = HB * HT;
    const int nv = n >> 2;
    const float4* hr4 = (const float4*)hr;
    const int4*   d4p = (const int4*)dur;
    const int4*   e4p = (const int4*)ev;

    auto process = [&](const float4& h, const int4& d, const int4& e) {
        float hh[4] = { h.x, h.y, h.z, h.w };
        int   dd[4] = { d.x, d.y, d.z, d.w };
        int   ee[4] = { e.x, e.y, e.z, e.w };
#pragma unroll
        for (int u = 0; u < 4; ++u) {
            float eh = expf(hh[u]);
            u64 fx = (u64)((double)eh * FXSCALE + 0.5);
            int idx = dd[u] + (ee[u] << 11);               // + e*NT, branchless
            atomicAdd(&loc[idx], fx | ((u64)ee[u] << 56));
            hrE += (double)hh[u] * (double)ee[u];
            ec  += (double)ee[u];
        }
    };

    // n = 2^22: exactly 2 vec4 iterations per thread, staged as a pair.
    for (int i = bid * HT + tid; i < nv; i += 2 * stride) {
        const bool two = (i + stride) < nv;
        float4 h0 = hr4[i];
        int4   d0 = d4p[i];
        int4   e0 = e4p[i];
        float4 h1; int4 d1, e1;
        if (two) { h1 = hr4[i + stride]; d1 = d4p[i + stride]; e1 = e4p[i + stride]; }
        process(h0, d0, e0);
        if (two) process(h1, d1, e1);
    }
    for (int j = (nv << 2) + bid * HT + tid; j < n; j += stride) {  // scalar tail
        float h = hr[j]; int d = dur[j]; int e = ev[j];
        float eh = expf(h);
        u64 fx = (u64)((double)eh * FXSCALE + 0.5);
        atomicAdd(&loc[d + (e << 11)], fx | ((u64)e << 56));
        hrE += (double)h * (double)e;
        ec  += (double)e;
    }
    __syncthreads();

    const size_t base = (size_t)bid * NT;
    for (int k = tid; k < NT; k += HT) {
        s0_part[base + k] = loc[k];
        tn_part[base + k] = loc[NT + k];
    }

    hrE = wave_reduce(hrE);
    ec  = wave_reduce(ec);
    if ((tid & 63) == 0) { redH[tid >> 6] = hrE; redC[tid >> 6] = ec; }
    __syncthreads();
    if (tid == 0) {
        double hh = 0.0, cc = 0.0;
#pragma unroll
        for (int w = 0; w < HT / 64; ++w) { hh += redH[w]; cc += redC[w]; }
        hrE_part[bid]  = hh;
        eCnt_part[bid] = cc;
    }
}

// ---------------------------------------------------------------------------
// K2: exact u64 reduction of partials -> s_fin/T_fin (double), n_fin (u32).
// Block owns 64 bins; 16 j-groups of 64 lanes each, coalesced 512B runs.
// ---------------------------------------------------------------------------
__global__ __launch_bounds__(RT) void k_reduce(
    const u64* __restrict__ s0_part, const u64* __restrict__ tn_part,
    double* __restrict__ s_fin, double* __restrict__ T_fin,
    unsigned* __restrict__ n_fin)
{
    __shared__ u64      rs[16][64];
    __shared__ u64      rt[16][64];
    __shared__ unsigned rn[16][64];

    const int bi = threadIdx.x & 63;
    const int jg = threadIdx.x >> 6;
    const int t  = blockIdx.x * 64 + bi;

    u64 s = 0ull, T = 0ull;
    unsigned c = 0u;
#pragma unroll 4
    for (int m = 0; m < HB / 16; ++m) {
        int j = jg + (m << 4);
        size_t idx = (size_t)j * NT + t;
        s += s0_part[idx];
        u64 v = tn_part[idx];
        T += v & TMASK;
        c += (unsigned)(v >> 56);
    }
    rs[jg][bi] = s; rt[jg][bi] = T; rn[jg][bi] = c;
    __syncthreads();
    if (jg == 0) {
        u64 S = 0ull, TT = 0ull; unsigned C = 0u;
#pragma unroll
        for (int m = 0; m < 16; ++m) { S += rs[m][bi]; TT += rt[m][bi]; C += rn[m][bi]; }
        s_fin[t] = (double)(S + TT) * INV_FXSCALE;   // s = s0 + T
        T_fin[t] = (double)TT * INV_FXSCALE;
        n_fin[t] = C;
    }
}

// ---------------------------------------------------------------------------
// K3: each block redundantly suffix-scans s_fin (2048 doubles) in LDS, does
// the Efron correction for its 16 bins (one wave per bin), then the LAST
// block (ticket atomic, no spin) reduces everything and writes the loss.
// ---------------------------------------------------------------------------
__global__ __launch_bounds__(ET) void k_scan_efron_final(
    const double* __restrict__ s_fin, const double* __restrict__ T_fin,
    const unsigned* __restrict__ n_fin,
    double* __restrict__ corr_part, const double* __restrict__ hrE_part,
    const double* __restrict__ eCnt_part,
    unsigned* __restrict__ counter, float* __restrict__ out)
{
    __shared__ double sa[NT];
    __shared__ double sb[NT];
    __shared__ double red[16];
    __shared__ unsigned is_last;

    const int tid = threadIdx.x, bid = blockIdx.x;

    // --- suffix scan (Hillis-Steele, ping-pong) ---
    for (int i = tid; i < NT; i += ET) sa[i] = s_fin[i];
    __syncthreads();
    double* cur = sa;
    double* nxt = sb;
    for (int off = 1; off < NT; off <<= 1) {
        for (int i = tid; i < NT; i += ET) {
            double v = cur[i];
            if (i + off < NT) v += cur[i + off];
            nxt[i] = v;
        }
        __syncthreads();
        double* tmp = cur; cur = nxt; nxt = tmp;
    }

    // --- Efron correction: one wave per bin, 16 bins per block ---
    const int wv = tid >> 6;       // 0..15 : bin slot
    const int l  = tid & 63;
    const int t  = bid * 16 + wv;
    unsigned nt = n_fin[t];
    double acc = 0.0;
    if (nt > 0) {
        double Rt = cur[t];
        double Tt = T_fin[t];
        double inv = 1.0 / (double)nt;
        for (unsigned k = l; k < nt; k += 64)
            acc += (double)logf((float)(Rt - (double)k * inv * Tt));
    }
    acc = wave_reduce(acc);
    if (l == 0) red[wv] = acc;
    __syncthreads();
    if (tid == 0) {
        double c = 0.0;
#pragma unroll
        for (int m = 0; m < 16; ++m) c += red[m];
        corr_part[bid] = c;
    }
    __syncthreads();

    // --- last-block final reduction ---
    if (tid == 0) {
        __threadfence();
        unsigned ticket = atomicAdd(counter, 1u);
        is_last = (ticket == EB - 1) ? 1u : 0u;
    }
    __syncthreads();
    if (is_last) {
        __threadfence();
        __shared__ double redA[16], redB[16], redC[16];
        double a = (tid < EB) ? corr_part[tid] : 0.0;
        double h = 0.0, c = 0.0;
        if (tid < HB) { h = hrE_part[tid]; c = eCnt_part[tid]; }
        a = wave_reduce(a); h = wave_reduce(h); c = wave_reduce(c);
        if ((tid & 63) == 0) { redA[tid >> 6] = a; redB[tid >> 6] = h; redC[tid >> 6] = c; }
        __syncthreads();
        if (tid == 0) {
            double A = 0.0, H = 0.0, C = 0.0;
#pragma unroll
            for (int w = 0; w < 16; ++w) { A += redA[w]; H += redB[w]; C += redC[w]; }
            out[0] = (float)(-(H - A) / (C + 1e-7));
        }
    }
}

// ---------------------------------------------------------------------------
extern "C" void kernel_launch(void* const* d_in, const int* in_sizes, int n_in,
                              void* d_out, int out_size, void* d_ws, size_t ws_size,
                              hipStream_t stream)
{
    const float* hr  = (const float*)d_in[0];
    const int*   dur = (const int*)d_in[1];
    const int*   ev  = (const int*)d_in[2];
    int n = in_sizes[1];

    char* ws = (char*)d_ws;
    u64*      s0_part   = (u64*)ws;                                  // 512*2048*8 = 8 MB
    u64*      tn_part   = (u64*)(ws + (size_t)8 * 1024 * 1024);      // 8 MB
    char*     p         = ws + (size_t)16 * 1024 * 1024;
    double*   s_fin     = (double*)p;          p += NT * 8;
    double*   T_fin     = (double*)p;          p += NT * 8;
    unsigned* n_fin     = (unsigned*)p;        p += NT * 4;
    double*   corr_part = (double*)p;          p += EB * 8;
    double*   hrE_part  = (double*)p;          p += HB * 8;
    double*   eCnt_part = (double*)p;          p += HB * 8;
    unsigned* counter   = (unsigned*)p;

    hipLaunchKernelGGL(k_hist, dim3(HB), dim3(HT), 0, stream,
                       hr, dur, ev, n, s0_part, tn_part, hrE_part, eCnt_part, counter);
    hipLaunchKernelGGL(k_reduce, dim3(RB), dim3(RT), 0, stream,
                       s0_part, tn_part, s_fin, T_fin, n_fin);
    hipLaunchKernelGGL(k_scan_efron_final, dim3(EB), dim3(ET), 0, stream,
                       s_fin, T_fin, n_fin, corr_part, hrE_part, eCnt_part,
                       counter, (float*)d_out);
}

// Round 6
// 38.497 us; speedup vs baseline: 4.3570x; 1.1226x over previous
//
#include <hip/hip_runtime.h>

#define NT 2048            // number of distinct event times
#define HB 512             // hist blocks (2 per CU)
#define HT 1024            // hist threads per block
#define RB 128             // reduce blocks (16 bins each)
#define RT 1024
#define EB 128             // efron blocks (16 bins each, 1 wave per bin)
#define ET 1024

#define SC      4096.0f              // 2^12 fixed-point scale (exact pow2 mult)
#define INV_SC  (1.0 / 4096.0)
#define TM26    ((1u << 26) - 1)     // tn pack: low 26 bits T, high 6 bits count

typedef unsigned long long u64;
typedef unsigned u32;

__device__ __forceinline__ double wave_reduce(double v) {
#pragma unroll
    for (int o = 32; o > 0; o >>= 1) v += __shfl_down(v, o, 64);
    return v;
}

// ---------------------------------------------------------------------------
// K1: per-block LDS histogram, ONE u32 atomic per sample, branchless, no f64.
//   loc[d + e*NT] += fx  (+ 1<<26 if event)
// fx = round(e^hr * 2^12). Censored half = s0; event half = (count<<26)|T.
// ---------------------------------------------------------------------------
__global__ __launch_bounds__(HT) void k_hist(
    const float* __restrict__ hr, const int* __restrict__ dur,
    const int* __restrict__ ev, int n,
    u32* __restrict__ s0_part, u32* __restrict__ tn_part,
    double* __restrict__ hrE_part, double* __restrict__ eCnt_part,
    unsigned* __restrict__ counter)
{
    __shared__ u32    loc[2 * NT];   // 16 KB
    __shared__ double redH[HT / 64], redC[HT / 64];

    const int tid = threadIdx.x, bid = blockIdx.x;
    if (bid == 0 && tid == 0) *counter = 0u;

    for (int i = tid; i < 2 * NT; i += HT) loc[i] = 0u;
    __syncthreads();

    float hrE = 0.f;
    int   ec  = 0;
    const int stride = HB * HT;
    const int nv = n >> 2;
    const float4* hr4 = (const float4*)hr;
    const int4*   d4p = (const int4*)dur;
    const int4*   e4p = (const int4*)ev;

    auto process = [&](const float4& h, const int4& d, const int4& e) {
        float hh[4] = { h.x, h.y, h.z, h.w };
        int   dd[4] = { d.x, d.y, d.z, d.w };
        int   ee[4] = { e.x, e.y, e.z, e.w };
#pragma unroll
        for (int u = 0; u < 4; ++u) {
            float eh = expf(hh[u]);
            u32 fx = (u32)(eh * SC + 0.5f);
            int idx = dd[u] + (ee[u] << 11);              // + e*NT, branchless
            atomicAdd(&loc[idx], fx + ((u32)ee[u] << 26));
            hrE += hh[u] * (float)ee[u];
            ec  += ee[u];
        }
    };

    // n = 2^22: exactly 2 vec4 iterations per thread, staged as a pair.
    for (int i = bid * HT + tid; i < nv; i += 2 * stride) {
        const bool two = (i + stride) < nv;
        float4 h0 = hr4[i];
        int4   d0 = d4p[i];
        int4   e0 = e4p[i];
        float4 h1; int4 d1, e1;
        if (two) { h1 = hr4[i + stride]; d1 = d4p[i + stride]; e1 = e4p[i + stride]; }
        process(h0, d0, e0);
        if (two) process(h1, d1, e1);
    }
    for (int j = (nv << 2) + bid * HT + tid; j < n; j += stride) {  // scalar tail
        float h = hr[j]; int d = dur[j]; int e = ev[j];
        float eh = expf(h);
        atomicAdd(&loc[d + (e << 11)], (u32)(eh * SC + 0.5f) + ((u32)e << 26));
        hrE += h * (float)e;
        ec  += e;
    }
    __syncthreads();

    const size_t base = (size_t)bid * NT;
    for (int k = tid; k < NT; k += HT) {
        s0_part[base + k] = loc[k];
        tn_part[base + k] = loc[NT + k];
    }

    double hrEd = wave_reduce((double)hrE);
    double ecd  = wave_reduce((double)ec);
    if ((tid & 63) == 0) { redH[tid >> 6] = hrEd; redC[tid >> 6] = ecd; }
    __syncthreads();
    if (tid == 0) {
        double hh = 0.0, cc = 0.0;
#pragma unroll
        for (int w = 0; w < HT / 64; ++w) { hh += redH[w]; cc += redC[w]; }
        hrE_part[bid]  = hh;
        eCnt_part[bid] = cc;
    }
}

// ---------------------------------------------------------------------------
// K2: reduce u32 partials -> s_fin/T_fin (double), n_fin (u32).
// 128 blocks x 16 bins. Wave covers 4 rows x 16 bins = 64B coalesced runs.
// ---------------------------------------------------------------------------
__global__ __launch_bounds__(RT) void k_reduce(
    const u32* __restrict__ s0_part, const u32* __restrict__ tn_part,
    double* __restrict__ s_fin, double* __restrict__ T_fin,
    unsigned* __restrict__ n_fin)
{
    __shared__ u64      rs[64][16];   // 8 KB
    __shared__ u64      rt[64][16];   // 8 KB
    __shared__ unsigned rn[64][16];   // 4 KB

    const int bi = threadIdx.x & 15;
    const int jg = threadIdx.x >> 4;         // 0..63
    const int t  = blockIdx.x * 16 + bi;

    u64 s = 0ull, T = 0ull;
    unsigned c = 0u;
#pragma unroll
    for (int m = 0; m < HB / 64; ++m) {      // 8 iterations
        int j = jg + (m << 6);
        size_t idx = (size_t)j * NT + t;
        s += s0_part[idx];
        u32 v = tn_part[idx];
        T += v & TM26;
        c += v >> 26;
    }
    rs[jg][bi] = s; rt[jg][bi] = T; rn[jg][bi] = c;
    __syncthreads();

    const int wv = threadIdx.x >> 6;         // 0..15 : bin slot
    const int l  = threadIdx.x & 63;
    u64 S  = rs[l][wv];
    u64 TT = rt[l][wv];
    u64 C  = rn[l][wv];
#pragma unroll
    for (int o = 32; o > 0; o >>= 1) {
        S  += __shfl_down(S,  o, 64);
        TT += __shfl_down(TT, o, 64);
        C  += __shfl_down(C,  o, 64);
    }
    if (l == 0) {
        int tt = blockIdx.x * 16 + wv;
        s_fin[tt] = (double)(S + TT) * INV_SC;   // s = s0 + T
        T_fin[tt] = (double)TT * INV_SC;
        n_fin[tt] = (unsigned)C;
    }
}

// ---------------------------------------------------------------------------
// K3: each block redundantly suffix-scans s_fin (2048 doubles) in LDS, does
// the Efron correction for its 16 bins (one wave per bin), then the LAST
// block (ticket atomic, no spin) reduces everything and writes the loss.
// ---------------------------------------------------------------------------
__global__ __launch_bounds__(ET) void k_scan_efron_final(
    const double* __restrict__ s_fin, const double* __restrict__ T_fin,
    const unsigned* __restrict__ n_fin,
    double* __restrict__ corr_part, const double* __restrict__ hrE_part,
    const double* __restrict__ eCnt_part,
    unsigned* __restrict__ counter, float* __restrict__ out)
{
    __shared__ double sa[NT];
    __shared__ double sb[NT];
    __shared__ double red[16];
    __shared__ unsigned is_last;

    const int tid = threadIdx.x, bid = blockIdx.x;

    // --- suffix scan (Hillis-Steele, ping-pong) ---
    for (int i = tid; i < NT; i += ET) sa[i] = s_fin[i];
    __syncthreads();
    double* cur = sa;
    double* nxt = sb;
    for (int off = 1; off < NT; off <<= 1) {
        for (int i = tid; i < NT; i += ET) {
            double v = cur[i];
            if (i + off < NT) v += cur[i + off];
            nxt[i] = v;
        }
        __syncthreads();
        double* tmp = cur; cur = nxt; nxt = tmp;
    }

    // --- Efron correction: one wave per bin, 16 bins per block ---
    const int wv = tid >> 6;
    const int l  = tid & 63;
    const int t  = bid * 16 + wv;
    unsigned nt = n_fin[t];
    double acc = 0.0;
    if (nt > 0) {
        double Rt = cur[t];
        double Tt = T_fin[t];
        double inv = 1.0 / (double)nt;
        for (unsigned k = l; k < nt; k += 64)
            acc += (double)logf((float)(Rt - (double)k * inv * Tt));
    }
    acc = wave_reduce(acc);
    if (l == 0) red[wv] = acc;
    __syncthreads();
    if (tid == 0) {
        double c = 0.0;
#pragma unroll
        for (int m = 0; m < 16; ++m) c += red[m];
        corr_part[bid] = c;
    }
    __syncthreads();

    // --- last-block final reduction ---
    if (tid == 0) {
        __threadfence();
        unsigned ticket = atomicAdd(counter, 1u);
        is_last = (ticket == EB - 1) ? 1u : 0u;
    }
    __syncthreads();
    if (is_last) {
        __threadfence();
        __shared__ double redA[16], redB[16], redC[16];
        double a = (tid < EB) ? corr_part[tid] : 0.0;
        double h = 0.0, c = 0.0;
        if (tid < HB) { h = hrE_part[tid]; c = eCnt_part[tid]; }
        a = wave_reduce(a); h = wave_reduce(h); c = wave_reduce(c);
        if ((tid & 63) == 0) { redA[tid >> 6] = a; redB[tid >> 6] = h; redC[tid >> 6] = c; }
        __syncthreads();
        if (tid == 0) {
            double A = 0.0, H = 0.0, C = 0.0;
#pragma unroll
            for (int w = 0; w < 16; ++w) { A += redA[w]; H += redB[w]; C += redC[w]; }
            out[0] = (float)(-(H - A) / (C + 1e-7));
        }
    }
}

// ---------------------------------------------------------------------------
extern "C" void kernel_launch(void* const* d_in, const int* in_sizes, int n_in,
                              void* d_out, int out_size, void* d_ws, size_t ws_size,
                              hipStream_t stream)
{
    const float* hr  = (const float*)d_in[0];
    const int*   dur = (const int*)d_in[1];
    const int*   ev  = (const int*)d_in[2];
    int n = in_sizes[1];

    char* ws = (char*)d_ws;
    u32*      s0_part   = (u32*)ws;                                  // 512*2048*4 = 4 MB
    u32*      tn_part   = (u32*)(ws + (size_t)4 * 1024 * 1024);      // 4 MB
    char*     p         = ws + (size_t)8 * 1024 * 1024;
    double*   s_fin     = (double*)p;          p += NT * 8;
    double*   T_fin     = (double*)p;          p += NT * 8;
    unsigned* n_fin     = (unsigned*)p;        p += NT * 4;
    double*   corr_part = (double*)p;          p += EB * 8;
    double*   hrE_part  = (double*)p;          p += HB * 8;
    double*   eCnt_part = (double*)p;          p += HB * 8;
    unsigned* counter   = (unsigned*)p;

    hipLaunchKernelGGL(k_hist, dim3(HB), dim3(HT), 0, stream,
                       hr, dur, ev, n, s0_part, tn_part, hrE_part, eCnt_part, counter);
    hipLaunchKernelGGL(k_reduce, dim3(RB), dim3(RT), 0, stream,
                       s0_part, tn_part, s_fin, T_fin, n_fin);
    hipLaunchKernelGGL(k_scan_efron_final, dim3(EB), dim3(ET), 0, stream,
                       s_fin, T_fin, n_fin, corr_part, hrE_part, eCnt_part,
                       counter, (float*)d_out);
}

// Round 7
// 35.857 us; speedup vs baseline: 4.6779x; 1.0736x over previous
//
#include <hip/hip_runtime.h>

#define NT 2048            // number of distinct event times
#define HB 256             // hist blocks (1 per CU)
#define HT 1024            // hist threads per block
#define RB 256             // reduce blocks (8 bins each)
#define RT 1024
#define EB 128             // efron blocks (16 bins each, 1 wave per bin)
#define ET 1024

#define SC      4096.0f              // 2^12 fixed-point scale (exact pow2 mult)
#define INV_SC  (1.0 / 4096.0)
#define TM26    ((1u << 26) - 1)     // tn pack: low 26 bits T, high 6 bits count

typedef unsigned long long u64;
typedef unsigned u32;

__device__ __forceinline__ double wave_reduce(double v) {
#pragma unroll
    for (int o = 32; o > 0; o >>= 1) v += __shfl_down(v, o, 64);
    return v;
}

// ---------------------------------------------------------------------------
// K1: software-pipelined per-block LDS histogram.
//  - 4 vec4 iterations per thread; next iteration's 3x16B loads issued BEFORE
//    processing the current one (VMEM latency hides under expf+atomic burst).
//  - dual histogram images (even/odd wave) halve LDS RMW serialization.
//  - one u32 atomic per sample: loc[img][d + e*NT] += fx + (e<<26).
// ---------------------------------------------------------------------------
__global__ __launch_bounds__(HT) void k_hist(
    const float* __restrict__ hr, const int* __restrict__ dur,
    const int* __restrict__ ev, int n,
    u32* __restrict__ s0_part, u32* __restrict__ tn_part,
    double* __restrict__ hrE_part, double* __restrict__ eCnt_part,
    unsigned* __restrict__ counter)
{
    __shared__ u32    loc[2][2 * NT];   // 32 KB, image per wave-parity
    __shared__ double redH[HT / 64], redC[HT / 64];

    const int tid = threadIdx.x, bid = blockIdx.x;
    if (bid == 0 && tid == 0) *counter = 0u;

    for (int i = tid; i < 2 * NT; i += HT) { loc[0][i] = 0u; loc[1][i] = 0u; }
    __syncthreads();

    u32* img = loc[(tid >> 6) & 1];

    float hrE = 0.f;
    int   ec  = 0;
    const int stride = HB * HT;
    const int nv = n >> 2;
    const float4* hr4 = (const float4*)hr;
    const int4*   d4p = (const int4*)dur;
    const int4*   e4p = (const int4*)ev;

    auto process = [&](const float4& h, const int4& d, const int4& e) {
        float hh[4] = { h.x, h.y, h.z, h.w };
        int   dd[4] = { d.x, d.y, d.z, d.w };
        int   ee[4] = { e.x, e.y, e.z, e.w };
#pragma unroll
        for (int u = 0; u < 4; ++u) {
            float eh = __expf(hh[u]);                     // fast hw exp
            u32 fx = (u32)(eh * SC + 0.5f);
            int idx = dd[u] + (ee[u] << 11);              // + e*NT, branchless
            atomicAdd(&img[idx], fx + ((u32)ee[u] << 26));
            hrE += hh[u] * (float)ee[u];
            ec  += ee[u];
        }
    };

    // n = 2^22: exactly 4 vec4 iterations; prefetch next before process(cur).
    int i = bid * HT + tid;
    if (i < nv) {
        float4 h_c = hr4[i];
        int4   d_c = d4p[i];
        int4   e_c = e4p[i];
        for (i += stride; i < nv; i += stride) {
            float4 h_n = hr4[i];
            int4   d_n = d4p[i];
            int4   e_n = e4p[i];
            process(h_c, d_c, e_c);       // overlaps with the 3 loads above
            h_c = h_n; d_c = d_n; e_c = e_n;
        }
        process(h_c, d_c, e_c);
    }
    for (int j = (nv << 2) + bid * HT + tid; j < n; j += stride) {  // tail
        float h = hr[j]; int d = dur[j]; int e = ev[j];
        float eh = __expf(h);
        atomicAdd(&loc[(tid >> 6) & 1][d + (e << 11)],
                  (u32)(eh * SC + 0.5f) + ((u32)e << 26));
        hrE += h * (float)e;
        ec  += e;
    }
    __syncthreads();

    // merge images field-wise (no cross-field carry) and write partials
    const size_t base = (size_t)bid * NT;
    for (int k = tid; k < NT; k += HT) {
        s0_part[base + k] = loc[0][k] + loc[1][k];
        u32 a = loc[0][NT + k], b = loc[1][NT + k];
        tn_part[base + k] = (((a >> 26) + (b >> 26)) << 26)
                          + ((a & TM26) + (b & TM26));
    }

    double hrEd = wave_reduce((double)hrE);
    double ecd  = wave_reduce((double)ec);
    if ((tid & 63) == 0) { redH[tid >> 6] = hrEd; redC[tid >> 6] = ecd; }
    __syncthreads();
    if (tid == 0) {
        double hh = 0.0, cc = 0.0;
#pragma unroll
        for (int w = 0; w < HT / 64; ++w) { hh += redH[w]; cc += redC[w]; }
        hrE_part[bid]  = hh;
        eCnt_part[bid] = cc;
    }
}

// ---------------------------------------------------------------------------
// K2: reduce u32 partials (256 rows) -> s_fin/T_fin (double), n_fin (u32).
// 256 blocks x 8 bins; 128 j-groups x 8 bins, 2 rows per thread, coalesced.
// ---------------------------------------------------------------------------
__global__ __launch_bounds__(RT) void k_reduce(
    const u32* __restrict__ s0_part, const u32* __restrict__ tn_part,
    double* __restrict__ s_fin, double* __restrict__ T_fin,
    unsigned* __restrict__ n_fin)
{
    __shared__ u64      rs[128][8];    // 8 KB
    __shared__ u64      rt[128][8];    // 8 KB
    __shared__ unsigned rn[128][8];    // 4 KB
    __shared__ u64      ps[8][2], pt[8][2];
    __shared__ unsigned pn[8][2];

    const int bi = threadIdx.x & 7;
    const int jg = threadIdx.x >> 3;          // 0..127
    const int t  = blockIdx.x * 8 + bi;

    u64 s = 0ull, T = 0ull;
    unsigned c = 0u;
#pragma unroll
    for (int m = 0; m < HB / 128; ++m) {      // 2 rows per thread
        int j = jg + (m << 7);
        size_t idx = (size_t)j * NT + t;
        s += s0_part[idx];
        u32 v = tn_part[idx];
        T += v & TM26;
        c += v >> 26;
    }
    rs[jg][bi] = s; rt[jg][bi] = T; rn[jg][bi] = c;
    __syncthreads();

    const int wv  = threadIdx.x >> 6;         // 0..15
    const int l   = threadIdx.x & 63;
    const int bin = wv >> 1;
    const int hf  = wv & 1;
    u64 S  = rs[hf * 64 + l][bin];
    u64 TT = rt[hf * 64 + l][bin];
    u64 C  = rn[hf * 64 + l][bin];
#pragma unroll
    for (int o = 32; o > 0; o >>= 1) {
        S  += __shfl_down(S,  o, 64);
        TT += __shfl_down(TT, o, 64);
        C  += __shfl_down(C,  o, 64);
    }
    if (l == 0) { ps[bin][hf] = S; pt[bin][hf] = TT; pn[bin][hf] = (unsigned)C; }
    __syncthreads();
    if (threadIdx.x < 8) {
        int b = threadIdx.x;
        u64 S2  = ps[b][0] + ps[b][1];
        u64 TT2 = pt[b][0] + pt[b][1];
        unsigned C2 = pn[b][0] + pn[b][1];
        int tt = blockIdx.x * 8 + b;
        s_fin[tt] = (double)(S2 + TT2) * INV_SC;   // s = s0 + T
        T_fin[tt] = (double)TT2 * INV_SC;
        n_fin[tt] = C2;
    }
}

// ---------------------------------------------------------------------------
// K3: each block redundantly suffix-scans s_fin (2048 doubles) in LDS, does
// the Efron correction for its 16 bins (one wave per bin), then the LAST
// block (ticket atomic, no spin) reduces everything and writes the loss.
// ---------------------------------------------------------------------------
__global__ __launch_bounds__(ET) void k_scan_efron_final(
    const double* __restrict__ s_fin, const double* __restrict__ T_fin,
    const unsigned* __restrict__ n_fin,
    double* __restrict__ corr_part, const double* __restrict__ hrE_part,
    const double* __restrict__ eCnt_part,
    unsigned* __restrict__ counter, float* __restrict__ out)
{
    __shared__ double sa[NT];
    __shared__ double sb[NT];
    __shared__ double red[16];
    __shared__ unsigned is_last;

    const int tid = threadIdx.x, bid = blockIdx.x;

    // --- suffix scan (Hillis-Steele, ping-pong) ---
    for (int i = tid; i < NT; i += ET) sa[i] = s_fin[i];
    __syncthreads();
    double* cur = sa;
    double* nxt = sb;
    for (int off = 1; off < NT; off <<= 1) {
        for (int i = tid; i < NT; i += ET) {
            double v = cur[i];
            if (i + off < NT) v += cur[i + off];
            nxt[i] = v;
        }
        __syncthreads();
        double* tmp = cur; cur = nxt; nxt = tmp;
    }

    // --- Efron correction: one wave per bin, 16 bins per block ---
    const int wv = tid >> 6;
    const int l  = tid & 63;
    const int t  = bid * 16 + wv;
    unsigned nt = n_fin[t];
    double acc = 0.0;
    if (nt > 0) {
        double Rt = cur[t];
        double Tt = T_fin[t];
        double inv = 1.0 / (double)nt;
        for (unsigned k = l; k < nt; k += 64)
            acc += (double)logf((float)(Rt - (double)k * inv * Tt));
    }
    acc = wave_reduce(acc);
    if (l == 0) red[wv] = acc;
    __syncthreads();
    if (tid == 0) {
        double c = 0.0;
#pragma unroll
        for (int m = 0; m < 16; ++m) c += red[m];
        corr_part[bid] = c;
    }
    __syncthreads();

    // --- last-block final reduction ---
    if (tid == 0) {
        __threadfence();
        unsigned ticket = atomicAdd(counter, 1u);
        is_last = (ticket == EB - 1) ? 1u : 0u;
    }
    __syncthreads();
    if (is_last) {
        __threadfence();
        __shared__ double redA[16], redB[16], redC[16];
        double a = (tid < EB) ? corr_part[tid] : 0.0;
        double h = 0.0, c = 0.0;
        if (tid < HB) { h = hrE_part[tid]; c = eCnt_part[tid]; }
        a = wave_reduce(a); h = wave_reduce(h); c = wave_reduce(c);
        if ((tid & 63) == 0) { redA[tid >> 6] = a; redB[tid >> 6] = h; redC[tid >> 6] = c; }
        __syncthreads();
        if (tid == 0) {
            double A = 0.0, H = 0.0, C = 0.0;
#pragma unroll
            for (int w = 0; w < 16; ++w) { A += redA[w]; H += redB[w]; C += redC[w]; }
            out[0] = (float)(-(H - A) / (C + 1e-7));
        }
    }
}

// ---------------------------------------------------------------------------
extern "C" void kernel_launch(void* const* d_in, const int* in_sizes, int n_in,
                              void* d_out, int out_size, void* d_ws, size_t ws_size,
                              hipStream_t stream)
{
    const float* hr  = (const float*)d_in[0];
    const int*   dur = (const int*)d_in[1];
    const int*   ev  = (const int*)d_in[2];
    int n = in_sizes[1];

    char* ws = (char*)d_ws;
    u32*      s0_part   = (u32*)ws;                                  // 256*2048*4 = 2 MB
    u32*      tn_part   = (u32*)(ws + (size_t)2 * 1024 * 1024);      // 2 MB
    char*     p         = ws + (size_t)4 * 1024 * 1024;
    double*   s_fin     = (double*)p;          p += NT * 8;
    double*   T_fin     = (double*)p;          p += NT * 8;
    unsigned* n_fin     = (unsigned*)p;        p += NT * 4;
    double*   corr_part = (double*)p;          p += EB * 8;
    double*   hrE_part  = (double*)p;          p += HB * 8;
    double*   eCnt_part = (double*)p;          p += HB * 8;
    unsigned* counter   = (unsigned*)p;

    hipLaunchKernelGGL(k_hist, dim3(HB), dim3(HT), 0, stream,
                       hr, dur, ev, n, s0_part, tn_part, hrE_part, eCnt_part, counter);
    hipLaunchKernelGGL(k_reduce, dim3(RB), dim3(RT), 0, stream,
                       s0_part, tn_part, s_fin, T_fin, n_fin);
    hipLaunchKernelGGL(k_scan_efron_final, dim3(EB), dim3(ET), 0, stream,
                       s_fin, T_fin, n_fin, corr_part, hrE_part, eCnt_part,
                       counter, (float*)d_out);
}